// Round 6
// baseline (821.030 us; speedup 1.0000x reference)
//
#include <hip/hip_runtime.h>

// Fused entmax(alpha=1.3) attention, fp32. B=16, N=2048, D=64.
// R6: attn matrix zeroed by hipMemsetAsync before the kernel; kernel only
// scatter-writes the ~15 actives/row (packed path: ONE predicated store per
// wave for both rows). Solver packs row0 in lanes 0-31, row1 in lanes 32-63
// (half-butterfly reductions, 1 pow/lane/sweep). Phase-1 g-loop unroll 4
// (LDS offsets become immediates). Fallbacks: A<=128 two-slot path, dense.

#define NBATCH 16
#define NSEQ   2048
#define DHEAD  64
#define OUT_OFF (NBATCH * NSEQ * DHEAD)   // out first, attn second
#define INV_A    3.3333333f               // 1/(alpha-1)
#define INV_A_M1 2.3333333f
#define TK    128
#define PADK  68                          // K-tile LDS stride (0 conflicts, R2/R5)
#define NTILE (NSEQ / TK)                 // 16

__device__ __forceinline__ float fast_log2(float x) { return __builtin_amdgcn_logf(x); }
__device__ __forceinline__ float fast_exp2(float x) { return __builtin_amdgcn_exp2f(x); }

__global__ __launch_bounds__(256) void entmax_attn_kernel(
    const float* __restrict__ Q, const float* __restrict__ K,
    const float* __restrict__ V, float* __restrict__ Out)
{
    // 8704 floats. Phase 1: K tile (128 x 68).
    // After: per-wave fallback slice fb = smem[w*2048 .. +2048)
    //        packed lists pck = smem[8192 + w*128 .. +128):
    //          [0..32) p row0 | [32..64) p row1 | [64..96) idx row0 | [96..128) idx row1
    __shared__ __align__(16) float smem[TK * PADK];
    __shared__ __align__(16) float q_lds[8][DHEAD];

    const int tid  = threadIdx.x;
    const int w    = tid >> 6;
    const int lane = tid & 63;

    // XCD pinning: batch b -> XCD b%8 (K/V L2-resident)
    const int i   = blockIdx.x;       // 0..4095
    const int xcd = i & 7;
    const int j2  = i >> 3;
    const int b   = xcd + 8 * (j2 & 1);
    const int rb  = j2 >> 1;          // 0..255
    const int n0  = rb * 8;

    const float* Kb = K + (size_t)b * NSEQ * DHEAD;
    const float* Vb = V + (size_t)b * NSEQ * DHEAD;

    if (tid < 128) {
        const int r = tid >> 4, g = tid & 15;
        ((float4*)q_lds[r])[g] =
            ((const float4*)(Q + ((size_t)b * NSEQ + (size_t)(n0 + r)) * DHEAD))[g];
    }

    // scores s[r][j]: q-row n0+2w+r vs key m = j*64+lane. Compile-time indices
    // only (runtime indexing demoted this to scratch in R2 — keep it unrolled).
    float s[2][32];
    const float* q0p = q_lds[2 * w + 0];
    const float* q1p = q_lds[2 * w + 1];

    // ---------------- phase 1: QK^T, K tiled through LDS ----------------
    #pragma unroll
    for (int t = 0; t < NTILE; ++t) {
        __syncthreads();
        #pragma unroll 4
        for (int rep = 0; rep < 8; ++rep) {
            const int f = tid + rep * 256;
            const int m = f >> 4, g = f & 15;
            const float4 kv = ((const float4*)(Kb + (size_t)(t * TK + m) * DHEAD))[g];
            *(float4*)&smem[m * PADK + 4 * g] = kv;
        }
        __syncthreads();

        float a00 = 0.f, a01 = 0.f, a10 = 0.f, a11 = 0.f;
        #pragma unroll 4   // amortizes LDS addressing; offsets become immediates
        for (int g = 0; g < 16; ++g) {
            const float4 k0 = *(const float4*)&smem[lane * PADK + 4 * g];
            const float4 k1 = *(const float4*)&smem[(64 + lane) * PADK + 4 * g];
            const float4 qa = *(const float4*)&q0p[4 * g];
            const float4 qb = *(const float4*)&q1p[4 * g];
            a00 += qa.x*k0.x + qa.y*k0.y + qa.z*k0.z + qa.w*k0.w;
            a01 += qa.x*k1.x + qa.y*k1.y + qa.z*k1.z + qa.w*k1.w;
            a10 += qb.x*k0.x + qb.y*k0.y + qb.z*k0.z + qb.w*k0.w;
            a11 += qb.x*k1.x + qb.y*k1.y + qb.z*k1.z + qb.w*k1.w;
        }
        s[0][2*t]   = a00 * 0.125f;
        s[0][2*t+1] = a01 * 0.125f;
        s[1][2*t]   = a10 * 0.125f;
        s[1][2*t+1] = a11 * 0.125f;
    }
    __syncthreads();   // K reads done; smem becomes per-wave regions

    float* fb  = &smem[w * 2048];          // fallback lists / dense p slice
    float* pck = &smem[8192 + w * 128];    // packed lists

    const unsigned long long lt = (1ull << lane) - 1ull;
    const int na = n0 + 2 * w;

    // row max + subtract (both rows, butterfly -> identical in all lanes)
    float mxa = s[0][0], mxb = s[1][0];
    #pragma unroll
    for (int j = 1; j < 32; ++j) { mxa = fmaxf(mxa, s[0][j]); mxb = fmaxf(mxb, s[1][j]); }
    #pragma unroll
    for (int off = 32; off >= 1; off >>= 1) {
        mxa = fmaxf(mxa, __shfl_xor(mxa, off, 64));
        mxb = fmaxf(mxb, __shfl_xor(mxb, off, 64));
    }
    #pragma unroll
    for (int j = 0; j < 32; ++j) { s[0][j] -= mxa; s[1][j] -= mxb; }

    // ballot-compact actives (> -1; provably tau* >= -1) into packed lists;
    // count exact A0, A1
    int A0 = 0, A1 = 0;
    #pragma unroll
    for (int j = 0; j < 32; ++j) {
        const bool a0 = s[0][j] > -1.0f;
        const unsigned long long bm0 = __ballot(a0);
        if (bm0) {
            const int pos = A0 + __popcll(bm0 & lt);
            if (a0 && pos < 32) { pck[pos] = s[0][j]; pck[64 + pos] = (float)(j*64 + lane); }
            A0 += __popcll(bm0);
        }
        const bool a1 = s[1][j] > -1.0f;
        const unsigned long long bm1 = __ballot(a1);
        if (bm1) {
            const int pos = A1 + __popcll(bm1 & lt);
            if (a1 && pos < 32) { pck[32 + pos] = s[1][j]; pck[96 + pos] = (float)(j*64 + lane); }
            A1 += __popcll(bm1);
        }
    }

    float* arow0 = Out + OUT_OFF + ((size_t)b * NSEQ + na) * NSEQ;
    float* arow1 = arow0 + NSEQ;

    if (A0 <= 32 && A1 <= 32) {
        // ---------- packed path: row0 in lanes 0-31, row1 in lanes 32-63 ----
        const bool r1 = lane >= 32;
        const int  li = lane & 31;
        const int  Ah = r1 ? A1 : A0;
        const bool ok = li < Ah;
        const float cv = pck[lane];              // layout makes this just [lane]
        const int   ci = ok ? (int)pck[64 + lane] : 0;

        float lo = -1.0f, hi = -1e-6f;           // half-uniform state
        #pragma unroll 1
        for (int it = 0; it < 12; ++it) {
            const float tau = 0.5f * (lo + hi);
            const float t = cv - tau;
            float S = (ok && t > 0.f) ? fast_exp2(INV_A * fast_log2(t)) : 0.f;
            #pragma unroll
            for (int off = 1; off <= 16; off <<= 1) S += __shfl_xor(S, off, 64);
            const bool big = S > 1.f;            // half-uniform
            lo = big ? tau : lo;
            hi = big ? hi : tau;
        }
        float tau = lo;
        #pragma unroll 1
        for (int it = 0; it < 2; ++it) {
            const float t = cv - tau;
            float S1 = 0.f, S2 = 0.f;
            if (ok && t > 0.f) {
                const float l = fast_log2(t);
                S1 = fast_exp2(INV_A * l);
                S2 = fast_exp2(INV_A_M1 * l);
            }
            #pragma unroll
            for (int off = 1; off <= 16; off <<= 1) {
                S1 += __shfl_xor(S1, off, 64);
                S2 += __shfl_xor(S2, off, 64);
            }
            tau += (S1 - 1.f) / (INV_A * S2);
            tau = fmaxf(fminf(tau, hi), lo);
        }
        const float tf = cv - tau;
        float p = (ok && tf > 0.f) ? fast_exp2(INV_A * fast_log2(tf)) : 0.f;
        float S = p;
        #pragma unroll
        for (int off = 1; off <= 16; off <<= 1) S += __shfl_xor(S, off, 64);
        const float pn = p / (S + 1e-12f);
        if (ok) pck[lane] = pn;                  // lists now hold normalized p

        // scatter the actives over the memset zeros: ONE predicated store
        if (ok) {
            float* ar = r1 ? arow1 : arow0;
            __builtin_nontemporal_store(pn, &ar[ci]);
        }

        // sparse PV for both rows, broadcast p/idx from LDS
        float o0 = 0.f, o1 = 0.f;
        const int Am = (A0 > A1) ? A0 : A1;
        #pragma unroll 2
        for (int ii = 0; ii < Am; ++ii) {
            const float pp0 = pck[ii];
            const float pp1 = pck[32 + ii];
            const int   ix0 = (int)pck[64 + ii];
            const int   ix1 = (int)pck[96 + ii];
            if (ii < A0) o0 += pp0 * Vb[(size_t)ix0 * DHEAD + lane];
            if (ii < A1) o1 += pp1 * Vb[(size_t)ix1 * DHEAD + lane];
        }
        Out[((size_t)b * NSEQ + na    ) * DHEAD + lane] = o0;
        Out[((size_t)b * NSEQ + na + 1) * DHEAD + lane] = o1;
    } else {
        // ---------------- fallback per row (rare) ----------------
        #pragma unroll 1
        for (int r = 0; r < 2; ++r) {
            float* arow = r ? arow1 : arow0;
            const int A = r ? A1 : A0;
            float outacc = 0.f;

            if (A <= 128) {
                // two-slot sparse path (R5), lists in fb
                float* cval = fb;
                float* cidx = fb + 128;
                int base = 0;
                #pragma unroll
                for (int j = 0; j < 32; ++j) {
                    const bool act = s[r][j] > -1.0f;
                    const unsigned long long bm = __ballot(act);
                    if (bm) {
                        const int pos = base + __popcll(bm & lt);
                        if (act) { cval[pos] = s[r][j]; cidx[pos] = (float)(j*64 + lane); }
                        base += __popcll(bm);
                    }
                }
                const float cv0 = cval[lane];
                const float cv1 = cval[64 + lane];
                const bool ok0 = (lane < A);
                const bool ok1 = (64 + lane < A);

                float lo = -1.0f, hi = -1e-6f;
                #pragma unroll 1
                for (int it = 0; it < 12; ++it) {
                    const float tau = 0.5f * (lo + hi);
                    const float t0 = cv0 - tau, t1 = cv1 - tau;
                    float S = ((ok0 && t0 > 0.f) ? fast_exp2(INV_A * fast_log2(t0)) : 0.f)
                            + ((ok1 && t1 > 0.f) ? fast_exp2(INV_A * fast_log2(t1)) : 0.f);
                    #pragma unroll
                    for (int off = 32; off >= 1; off >>= 1) S += __shfl_xor(S, off, 64);
                    if (S > 1.f) lo = tau; else hi = tau;
                }
                float tau = lo;
                #pragma unroll 1
                for (int it = 0; it < 2; ++it) {
                    const float t0 = cv0 - tau, t1 = cv1 - tau;
                    float S1 = 0.f, S2 = 0.f;
                    if (ok0 && t0 > 0.f) {
                        const float l = fast_log2(t0);
                        S1 += fast_exp2(INV_A * l); S2 += fast_exp2(INV_A_M1 * l);
                    }
                    if (ok1 && t1 > 0.f) {
                        const float l = fast_log2(t1);
                        S1 += fast_exp2(INV_A * l); S2 += fast_exp2(INV_A_M1 * l);
                    }
                    #pragma unroll
                    for (int off = 32; off >= 1; off >>= 1) {
                        S1 += __shfl_xor(S1, off, 64);
                        S2 += __shfl_xor(S2, off, 64);
                    }
                    tau += (S1 - 1.f) / (INV_A * S2);
                    tau = fmaxf(fminf(tau, hi), lo);
                }
                const float t0 = cv0 - tau, t1 = cv1 - tau;
                float p0 = (ok0 && t0 > 0.f) ? fast_exp2(INV_A * fast_log2(t0)) : 0.f;
                float p1 = (ok1 && t1 > 0.f) ? fast_exp2(INV_A * fast_log2(t1)) : 0.f;
                float S = p0 + p1;
                #pragma unroll
                for (int off = 32; off >= 1; off >>= 1) S += __shfl_xor(S, off, 64);
                const float rnorm = 1.f / (S + 1e-12f);
                p0 *= rnorm; p1 *= rnorm;
                const int i0 = ok0 ? (int)cidx[lane] : 0;
                const int i1 = ok1 ? (int)cidx[64 + lane] : 0;
                if (ok0) { cval[lane] = p0;      __builtin_nontemporal_store(p0, &arow[i0]); }
                if (ok1) { cval[64 + lane] = p1; __builtin_nontemporal_store(p1, &arow[i1]); }

                #pragma unroll 2
                for (int ii = 0; ii < A; ++ii)
                    outacc += cval[ii] * Vb[(size_t)(int)cidx[ii] * DHEAD + lane];
            } else {
                // dense path: full-row compute + dense store + dense PV via fb
                float lo = -1.0f, hi = -1e-6f;
                #pragma unroll 1
                for (int it = 0; it < 12; ++it) {
                    const float tau = 0.5f * (lo + hi);
                    float S = 0.f;
                    #pragma unroll
                    for (int j = 0; j < 32; ++j) {
                        const float t = s[r][j] - tau;
                        const float p = fast_exp2(INV_A * fast_log2(t));
                        S += (t > 0.f) ? p : 0.f;
                    }
                    #pragma unroll
                    for (int off = 32; off >= 1; off >>= 1) S += __shfl_xor(S, off, 64);
                    if (S > 1.f) lo = tau; else hi = tau;
                }
                float tau = lo;
                #pragma unroll 1
                for (int it = 0; it < 2; ++it) {
                    float S1 = 0.f, S2 = 0.f;
                    #pragma unroll
                    for (int j = 0; j < 32; ++j) {
                        const float t = s[r][j] - tau;
                        if (t > 0.f) {
                            const float l = fast_log2(t);
                            S1 += fast_exp2(INV_A * l); S2 += fast_exp2(INV_A_M1 * l);
                        }
                    }
                    #pragma unroll
                    for (int off = 32; off >= 1; off >>= 1) {
                        S1 += __shfl_xor(S1, off, 64);
                        S2 += __shfl_xor(S2, off, 64);
                    }
                    tau += (S1 - 1.f) / (INV_A * S2);
                    tau = fmaxf(fminf(tau, hi), lo);
                }
                float S = 0.f;
                #pragma unroll
                for (int j = 0; j < 32; ++j) {
                    const float t = s[r][j] - tau;
                    const float p = (t > 0.f) ? fast_exp2(INV_A * fast_log2(t)) : 0.f;
                    s[r][j] = p;
                    S += p;
                }
                #pragma unroll
                for (int off = 32; off >= 1; off >>= 1) S += __shfl_xor(S, off, 64);
                const float rnorm = 1.f / (S + 1e-12f);

                #pragma unroll
                for (int j = 0; j < 32; ++j) {
                    const float pv = s[r][j] * rnorm;
                    fb[j * 64 + lane] = pv;
                    __builtin_nontemporal_store(pv, &arow[j * 64 + lane]);
                }
                #pragma unroll 4
                for (int m = 0; m < NSEQ; ++m)
                    outacc += fb[m] * Vb[(size_t)m * DHEAD + lane];
            }
            Out[((size_t)b * NSEQ + na + r) * DHEAD + lane] = outacc;
        }
    }
}

extern "C" void kernel_launch(void* const* d_in, const int* in_sizes, int n_in,
                              void* d_out, int out_size, void* d_ws, size_t ws_size,
                              hipStream_t stream) {
    const float* q = (const float*)d_in[0];
    const float* k = (const float*)d_in[1];
    const float* v = (const float*)d_in[2];
    float* out = (float*)d_out;
    (void)in_sizes; (void)n_in; (void)out_size; (void)d_ws; (void)ws_size;
    // zero the attn region (kernel scatter-writes only the ~15 actives/row)
    hipMemsetAsync((void*)(out + OUT_OFF), 0,
                   (size_t)NBATCH * NSEQ * NSEQ * sizeof(float), stream);
    dim3 grid(4096), block(256);
    hipLaunchKernelGGL(entmax_attn_kernel, grid, block, 0, stream, q, k, v, out);
}

// Round 7
// 566.944 us; speedup vs baseline: 1.4482x; 1.4482x over previous
//
#include <hip/hip_runtime.h>

// Fused entmax(alpha=1.3) attention, fp32. B=16, N=2048, D=64.
// R7 = R5 structure (VGPR-safe, 379 us) + async K staging:
// __builtin_amdgcn_global_load_lds width=16 (no VGPR round-trip), LDS tile
// kept contiguous (DMA needs lane-contiguous dest); bank conflicts avoided
// by XOR swizzle (row m chunk g stored at slot g^(m&15), applied on the
// GLOBAL source offsets — free). Read: slot g^(lane&15) -> same 8-lanes-per-
// bank-group distribution as the old +4 pad (measured ~0 conflicts).
// DO NOT raise phase-1 unroll: scores s[2][32] sit at the register cliff
// (R2/R4/R6 all spilled from small pressure increases; canary = WRITE_SIZE).

#define NBATCH 16
#define NSEQ   2048
#define DHEAD  64
#define OUT_OFF (NBATCH * NSEQ * DHEAD)   // out first, attn second
#define INV_A    3.3333333f               // 1/(alpha-1)
#define INV_A_M1 2.3333333f
#define TK    128
#define NTILE (NSEQ / TK)                 // 16

__device__ __forceinline__ float fast_log2(float x) { return __builtin_amdgcn_logf(x); }
__device__ __forceinline__ float fast_exp2(float x) { return __builtin_amdgcn_exp2f(x); }

__device__ __forceinline__ void async_load16(const float* g, float* l) {
    __builtin_amdgcn_global_load_lds(
        (const __attribute__((address_space(1))) void*)g,
        (__attribute__((address_space(3))) void*)l, 16, 0, 0);
}

__global__ __launch_bounds__(256) void entmax_attn_kernel(
    const float* __restrict__ Q, const float* __restrict__ K,
    const float* __restrict__ V, float* __restrict__ Out)
{
    // phase 1: contiguous K tile, 128 rows x 64 floats (32 KB), XOR-swizzled
    // slot order within each row. phase 2/3: per-wave 2048-float regions:
    //   [0..1024) prow | [1024..1152) cval | [1152..1280) cidx
    __shared__ __align__(16) float smem[TK * DHEAD];
    __shared__ __align__(16) float q_lds[8][DHEAD];

    const int tid  = threadIdx.x;
    const int w    = tid >> 6;
    const int lane = tid & 63;
    const int l15  = lane & 15;

    // XCD pinning: batch b -> XCD b%8 (K/V L2-resident)
    const int i   = blockIdx.x;       // 0..4095
    const int xcd = i & 7;
    const int j2  = i >> 3;
    const int b   = xcd + 8 * (j2 & 1);
    const int rb  = j2 >> 1;          // 0..255
    const int n0  = rb * 8;

    const float* Kb = K + (size_t)b * NSEQ * DHEAD;
    const float* Vb = V + (size_t)b * NSEQ * DHEAD;

    if (tid < 128) {
        const int r = tid >> 4, g = tid & 15;
        ((float4*)q_lds[r])[g] =
            ((const float4*)(Q + ((size_t)b * NSEQ + (size_t)(n0 + r)) * DHEAD))[g];
    }

    // global source offsets (floats, within tile) for the swizzled DMA:
    // lane's LDS dest is slot f = rep*256+tid (contiguous); it must receive
    // row m = f>>4, original chunk g_orig = (f&15) ^ (m&15).
    int src_off[8];
    #pragma unroll
    for (int rep = 0; rep < 8; ++rep) {
        const int f = tid + rep * 256;
        const int m = f >> 4;
        const int go = (f & 15) ^ (m & 15);
        src_off[rep] = m * DHEAD + 4 * go;
    }

    // scores s[r][j]: q-row n0+2w+r vs key m = j*64+lane. Compile-time
    // indices only (runtime indexing -> scratch demotion, R2).
    float s[2][32];
    const float* q0p = q_lds[2 * w + 0];
    const float* q1p = q_lds[2 * w + 1];

    // ---------------- phase 1: QK^T, K tiled through LDS (async DMA) -------
    #pragma unroll
    for (int t = 0; t < NTILE; ++t) {
        __syncthreads();   // prev tile consumed (t=0: covers q staging)
        const float* Kt = Kb + (size_t)t * TK * DHEAD;
        #pragma unroll
        for (int rep = 0; rep < 8; ++rep)
            async_load16(Kt + src_off[rep], &smem[4 * (tid + rep * 256)]);
        __syncthreads();   // barrier drains vmcnt -> DMA complete

        float a00 = 0.f, a01 = 0.f, a10 = 0.f, a11 = 0.f;
        #pragma unroll 1   // rolled: q from LDS broadcast each g, low VGPR
        for (int g = 0; g < 16; ++g) {
            const int gs = 4 * (g ^ l15);                       // swizzled slot
            const float4 k0 = *(const float4*)&smem[lane * DHEAD + gs];
            const float4 k1 = *(const float4*)&smem[(64 + lane) * DHEAD + gs];
            const float4 qa = *(const float4*)&q0p[4 * g];      // uniform bcast
            const float4 qb = *(const float4*)&q1p[4 * g];
            a00 += qa.x*k0.x + qa.y*k0.y + qa.z*k0.z + qa.w*k0.w;
            a01 += qa.x*k1.x + qa.y*k1.y + qa.z*k1.z + qa.w*k1.w;
            a10 += qb.x*k0.x + qb.y*k0.y + qb.z*k0.z + qb.w*k0.w;
            a11 += qb.x*k1.x + qb.y*k1.y + qb.z*k1.z + qb.w*k1.w;
        }
        s[0][2*t]   = a00 * 0.125f;
        s[0][2*t+1] = a01 * 0.125f;
        s[1][2*t]   = a10 * 0.125f;
        s[1][2*t+1] = a11 * 0.125f;
    }
    __syncthreads();   // K reads done; smem becomes per-wave regions

    float* wreg = &smem[w * 2048];
    float* prow = wreg;
    float* cval = wreg + 1024;
    float* cidx = wreg + 1152;
    const unsigned long long lt_mask = (1ull << lane) - 1ull;
    const int na = n0 + 2 * w;

    #pragma unroll
    for (int r = 0; r < 2; ++r) {
        // row max (butterfly -> identical in all lanes)
        float mx = s[r][0];
        #pragma unroll
        for (int j = 1; j < 32; ++j) mx = fmaxf(mx, s[r][j]);
        #pragma unroll
        for (int off = 32; off >= 1; off >>= 1) mx = fmaxf(mx, __shfl_xor(mx, off, 64));
        #pragma unroll
        for (int j = 0; j < 32; ++j) s[r][j] -= mx;

        // ballot-compact elements > -1 (only these can be in the support)
        int base = 0;
        #pragma unroll
        for (int j = 0; j < 32; ++j) {
            const bool act = s[r][j] > -1.0f;
            const unsigned long long bm = __ballot(act);
            const int pos = base + __popcll(bm & lt_mask);
            if (act && pos < 128) {
                cval[pos] = s[r][j];
                cidx[pos] = (float)(j * 64 + lane);
            }
            base += __popcll(bm);
        }
        const int A = base;               // wave-uniform
        float outacc = 0.f;

        if (A <= 128) {
            // -------- sparse solver on <=2 compact elements per lane --------
            const float cv0 = cval[lane];
            const float cv1 = cval[64 + lane];
            const bool ok0 = (lane < A);
            const bool ok1 = (64 + lane < A);

            float lo = -1.0f, hi = -1e-6f;
            #pragma unroll 1
            for (int it = 0; it < 12; ++it) {
                const float tau = 0.5f * (lo + hi);
                const float t0 = cv0 - tau, t1 = cv1 - tau;
                float S = ((ok0 && t0 > 0.f) ? fast_exp2(INV_A * fast_log2(t0)) : 0.f)
                        + ((ok1 && t1 > 0.f) ? fast_exp2(INV_A * fast_log2(t1)) : 0.f);
                #pragma unroll
                for (int off = 32; off >= 1; off >>= 1) S += __shfl_xor(S, off, 64);
                if (S > 1.f) lo = tau; else hi = tau;
            }
            float tau = lo;
            #pragma unroll 1
            for (int it = 0; it < 2; ++it) {
                const float t0 = cv0 - tau, t1 = cv1 - tau;
                float S1 = 0.f, S2 = 0.f;
                if (ok0 && t0 > 0.f) {
                    const float l = fast_log2(t0);
                    S1 += fast_exp2(INV_A * l); S2 += fast_exp2(INV_A_M1 * l);
                }
                if (ok1 && t1 > 0.f) {
                    const float l = fast_log2(t1);
                    S1 += fast_exp2(INV_A * l); S2 += fast_exp2(INV_A_M1 * l);
                }
                #pragma unroll
                for (int off = 32; off >= 1; off >>= 1) {
                    S1 += __shfl_xor(S1, off, 64);
                    S2 += __shfl_xor(S2, off, 64);
                }
                tau += (S1 - 1.f) / (INV_A * S2);
                tau = fmaxf(fminf(tau, hi), lo);
            }

            // final p on the compact set + normalize
            const float t0 = cv0 - tau, t1 = cv1 - tau;
            float p0 = (ok0 && t0 > 0.f) ? fast_exp2(INV_A * fast_log2(t0)) : 0.f;
            float p1 = (ok1 && t1 > 0.f) ? fast_exp2(INV_A * fast_log2(t1)) : 0.f;
            float S = p0 + p1;
            #pragma unroll
            for (int off = 32; off >= 1; off >>= 1) S += __shfl_xor(S, off, 64);
            const float rnorm = 1.f / (S + 1e-12f);
            p0 *= rnorm; p1 *= rnorm;
            const int i0 = ok0 ? (int)cidx[lane] : 0;
            const int i1 = ok1 ? (int)cidx[64 + lane] : 0;
            if (ok0) cval[lane] = p0;        // cval now holds normalized p
            if (ok1) cval[64 + lane] = p1;

            // -------- attn row: zeros + scatter, two 1024-float segments ----
            float* arow = Out + OUT_OFF + ((size_t)b * NSEQ + (na + r)) * NSEQ;
            #pragma unroll
            for (int seg = 0; seg < 2; ++seg) {
                #pragma unroll
                for (int z = 0; z < 4; ++z)
                    *(float4*)&prow[(z * 64 + lane) * 4] = make_float4(0.f, 0.f, 0.f, 0.f);
                if (ok0 && (i0 >> 10) == seg) prow[i0 & 1023] = p0;
                if (ok1 && (i1 >> 10) == seg) prow[i1 & 1023] = p1;
                #pragma unroll
                for (int z = 0; z < 16; ++z)
                    __builtin_nontemporal_store(prow[z * 64 + lane],
                                                &arow[seg * 1024 + z * 64 + lane]);
            }

            // -------- sparse PV: only active V rows; out dim d = lane -------
            int ii = 0;
            #pragma unroll 1
            for (; ii + 4 <= A; ii += 4) {
                const float pa = cval[ii + 0], pb = cval[ii + 1];
                const float pc = cval[ii + 2], pd = cval[ii + 3];
                const int ma = (int)cidx[ii + 0], mb = (int)cidx[ii + 1];
                const int mc = (int)cidx[ii + 2], md = (int)cidx[ii + 3];
                const float va  = Vb[(size_t)ma * DHEAD + lane];
                const float vb2 = Vb[(size_t)mb * DHEAD + lane];
                const float vc  = Vb[(size_t)mc * DHEAD + lane];
                const float vd  = Vb[(size_t)md * DHEAD + lane];
                outacc += pa * va + pb * vb2 + pc * vc + pd * vd;
            }
            #pragma unroll 1
            for (; ii < A; ++ii)
                outacc += cval[ii] * Vb[(size_t)(int)cidx[ii] * DHEAD + lane];
        } else {
            // -------- dense fallback (rare; correctness path) ---------------
            float lo = -1.0f, hi = -1e-6f;
            #pragma unroll 1
            for (int it = 0; it < 12; ++it) {
                const float tau = 0.5f * (lo + hi);
                float S = 0.f;
                #pragma unroll
                for (int j = 0; j < 32; ++j) {
                    const float t = s[r][j] - tau;
                    const float p = fast_exp2(INV_A * fast_log2(t));
                    S += (t > 0.f) ? p : 0.f;
                }
                #pragma unroll
                for (int off = 32; off >= 1; off >>= 1) S += __shfl_xor(S, off, 64);
                if (S > 1.f) lo = tau; else hi = tau;
            }
            float tau = lo;
            #pragma unroll 1
            for (int it = 0; it < 2; ++it) {
                float S1 = 0.f, S2 = 0.f;
                #pragma unroll
                for (int j = 0; j < 32; ++j) {
                    const float t = s[r][j] - tau;
                    if (t > 0.f) {
                        const float l = fast_log2(t);
                        S1 += fast_exp2(INV_A * l); S2 += fast_exp2(INV_A_M1 * l);
                    }
                }
                #pragma unroll
                for (int off = 32; off >= 1; off >>= 1) {
                    S1 += __shfl_xor(S1, off, 64);
                    S2 += __shfl_xor(S2, off, 64);
                }
                tau += (S1 - 1.f) / (INV_A * S2);
                tau = fmaxf(fminf(tau, hi), lo);
            }
            float S = 0.f;
            #pragma unroll
            for (int j = 0; j < 32; ++j) {
                const float t = s[r][j] - tau;
                const float p = (t > 0.f) ? fast_exp2(INV_A * fast_log2(t)) : 0.f;
                s[r][j] = p;
                S += p;
            }
            #pragma unroll
            for (int off = 32; off >= 1; off >>= 1) S += __shfl_xor(S, off, 64);
            const float rnorm = 1.f / (S + 1e-12f);

            float* arow = Out + OUT_OFF + ((size_t)b * NSEQ + (na + r)) * NSEQ;
            #pragma unroll
            for (int seg = 0; seg < 2; ++seg) {
                #pragma unroll
                for (int jj = 0; jj < 16; ++jj)
                    prow[jj * 64 + lane] = s[r][seg * 16 + jj] * rnorm;
                #pragma unroll
                for (int z = 0; z < 16; ++z)
                    __builtin_nontemporal_store(prow[z * 64 + lane],
                                                &arow[seg * 1024 + z * 64 + lane]);
                #pragma unroll 4
                for (int m = 0; m < 1024; ++m)
                    outacc += prow[m] * Vb[(size_t)(seg * 1024 + m) * DHEAD + lane];
            }
        }

        Out[((size_t)b * NSEQ + (na + r)) * DHEAD + lane] = outacc;
    }
}

extern "C" void kernel_launch(void* const* d_in, const int* in_sizes, int n_in,
                              void* d_out, int out_size, void* d_ws, size_t ws_size,
                              hipStream_t stream) {
    const float* q = (const float*)d_in[0];
    const float* k = (const float*)d_in[1];
    const float* v = (const float*)d_in[2];
    float* out = (float*)d_out;
    (void)in_sizes; (void)n_in; (void)out_size; (void)d_ws; (void)ws_size;
    dim3 grid(4096), block(256);
    hipLaunchKernelGGL(entmax_attn_kernel, grid, block, 0, stream, q, k, v, out);
}